// Round 1
// baseline (25.668 us; speedup 1.0000x reference)
//
#include <hip/hip_runtime.h>

#define LENY  1048576
#define NU    (LENY - 1)      // length of u_combined
#define NRBF  11
#define NB    1024            // blocks
#define NT    256             // threads per block
#define CHUNK 1024            // elements per block
#define PERT  4               // CHUNK / NT
#define UPAD(i) ((i) + ((i) >> 2))   // LDS anti-bank-conflict padding for float2

__device__ __forceinline__ float sigmoid10(float x) {
    x = fminf(10.0f, fmaxf(-10.0f, x));
    return 1.0f / (1.0f + expf(-x));
}

// Pass 1: compute u_combined, write it, and per-block double sums of B'*u.
__global__ __launch_bounds__(NT) void rbf_pass1(
    const float2* __restrict__ yin,
    const float2* __restrict__ xa,
    const float2* __restrict__ xb,
    const float*  __restrict__ rbfw_raw,
    const float*  __restrict__ weights,
    const float*  __restrict__ g1raw,
    const float*  __restrict__ g2raw,
    float2* __restrict__ uout,
    double2* __restrict__ bsums)
{
    const int b = blockIdx.x, t = threadIdx.x;

    // scalar params (uniform -> scalar loads, L2-cached)
    const float RBFw  = sigmoid10(rbfw_raw[0]);
    const float wdt   = RBFw * 2.0f / 10.0f;        // RBFw*(tmax-tmin)/(NRBF-1)
    const float denom = 2.0f * wdt * wdt;
    const float g1 = expf(g1raw[0]);
    const float g2 = expf(g2raw[0]);
    const float Bf = (float)(1.0 / 60.0);

    float wj[NRBF];
    #pragma unroll
    for (int j = 0; j < NRBF; ++j) wj[j] = weights[j];

    double sx = 0.0, sy = 0.0;
    const int base = b * CHUNK;
    #pragma unroll
    for (int r = 0; r < PERT; ++r) {
        const int gi = base + r * NT + t;
        if (gi < NU) {
            // t_i = (i - (LENY-1)/2) / ((LENY-1)/2)
            const float ti = ((float)gi - 524287.5f) / 524287.5f;
            float dot = 0.0f;
            #pragma unroll
            for (int j = 0; j < NRBF; ++j) {
                const float c = -1.0f + 0.2f * (float)j;  // linspace(-1,1,11)
                const float d = ti - c;
                dot += expf(-(d * d) / denom) * wj[j];
            }
            const float wt = sigmoid10(dot);

            const float2 y = yin[gi], a = xa[gi], bb = xb[gi];
            const float u1x = -g1 * (y.x - a.x);
            const float u1y = -g1 * (y.y - a.y);
            const float u2x = -g2 * (y.x - bb.x);
            const float u2y = -g2 * (y.y - bb.y);
            const float ux = u1x * (1.0f - wt) + u2x * wt;
            const float uy = u1y * (1.0f - wt) + u2y * wt;

            uout[gi] = make_float2(ux, uy);
            sx += (double)(ux * Bf);
            sy += (double)(uy * Bf);
        }
    }

    __shared__ double2 sred[NT];
    sred[t] = make_double2(sx, sy);
    __syncthreads();
    #pragma unroll
    for (int s = NT / 2; s > 0; s >>= 1) {
        if (t < s) { sred[t].x += sred[t + s].x; sred[t].y += sred[t + s].y; }
        __syncthreads();
    }
    if (t == 0) bsums[b] = sred[0];
}

// Pass 2: per-block prefix offset from bsums, in-block scan, write y.
__global__ __launch_bounds__(NT) void rbf_pass2(
    const float2* __restrict__ yin,
    const float2* __restrict__ uin,
    const double2* __restrict__ bsums,
    float2* __restrict__ yout)
{
    const int b = blockIdx.x, t = threadIdx.x;
    const float Bf = (float)(1.0 / 60.0);

    __shared__ float2  ubuf[CHUNK + (CHUNK >> 2)];
    __shared__ double2 sred[NT];

    // ---- block offset = sum(bsums[0..b-1]), deterministic order ----
    double ox = 0.0, oy = 0.0;
    for (int j = t; j < b; j += NT) { ox += bsums[j].x; oy += bsums[j].y; }
    sred[t] = make_double2(ox, oy);
    __syncthreads();
    #pragma unroll
    for (int s = NT / 2; s > 0; s >>= 1) {
        if (t < s) { sred[t].x += sred[t + s].x; sred[t].y += sred[t + s].y; }
        __syncthreads();
    }
    const double offx = sred[0].x;
    const double offy = sred[0].y;
    // (reads of sred[0] done; barrier below before sred is reused)

    // ---- load u chunk coalesced into LDS ----
    const int base = b * CHUNK;
    #pragma unroll
    for (int r = 0; r < PERT; ++r) {
        const int gi = base + r * NT + t;
        float2 v = make_float2(0.0f, 0.0f);
        if (gi < NU) v = uin[gi];
        ubuf[UPAD(r * NT + t)] = v;
    }
    __syncthreads();   // covers both ubuf readiness and sred reuse

    // ---- per-thread segment sums (scaled), in double ----
    double ssx = 0.0, ssy = 0.0;
    #pragma unroll
    for (int k = 0; k < PERT; ++k) {
        const float2 v = ubuf[UPAD(t * PERT + k)];
        ssx += (double)(v.x * Bf);
        ssy += (double)(v.y * Bf);
    }
    sred[t] = make_double2(ssx, ssy);
    __syncthreads();

    // ---- inclusive Hillis-Steele scan across 256 threads ----
    for (int off = 1; off < NT; off <<= 1) {
        double ax = 0.0, ay = 0.0;
        if (t >= off) { ax = sred[t - off].x; ay = sred[t - off].y; }
        __syncthreads();
        if (t >= off) { sred[t].x += ax; sred[t].y += ay; }
        __syncthreads();
    }

    double runx = offx + ((t > 0) ? sred[t - 1].x : 0.0);
    double runy = offy + ((t > 0) ? sred[t - 1].y : 0.0);
    const float2 y0 = yin[0];

    // ---- final sequential pass: overwrite LDS with y values ----
    #pragma unroll
    for (int k = 0; k < PERT; ++k) {
        const float2 v = ubuf[UPAD(t * PERT + k)];
        runx += (double)(v.x * Bf);
        runy += (double)(v.y * Bf);
        ubuf[UPAD(t * PERT + k)] =
            make_float2((float)((double)y0.x + runx),
                        (float)((double)y0.y + runy));
    }
    __syncthreads();

    // ---- coalesced write-out: y[g+1] for g in chunk ----
    #pragma unroll
    for (int r = 0; r < PERT; ++r) {
        const int gi = base + r * NT + t;
        if (gi < NU) yout[gi + 1] = ubuf[UPAD(r * NT + t)];
    }
    if (b == 0 && t == 0) yout[0] = yin[0];
}

extern "C" void kernel_launch(void* const* d_in, const int* in_sizes, int n_in,
                              void* d_out, int out_size, void* d_ws, size_t ws_size,
                              hipStream_t stream) {
    const float2* yin  = (const float2*)d_in[0];
    const float2* xa   = (const float2*)d_in[1];
    const float2* xb   = (const float2*)d_in[2];
    const float*  rbfw = (const float*)d_in[3];
    const float*  wts  = (const float*)d_in[4];
    const float*  g1   = (const float*)d_in[5];
    const float*  g2   = (const float*)d_in[6];

    float* out = (float*)d_out;
    float2* yout = (float2*)out;                  // y: LENY x 2
    float2* uout = (float2*)(out + 2 * LENY);     // u_combined: (LENY-1) x 2
    double2* bsums = (double2*)d_ws;              // NB double2 = 16 KB

    rbf_pass1<<<NB, NT, 0, stream>>>(yin, xa, xb, rbfw, wts, g1, g2, uout, bsums);
    rbf_pass2<<<NB, NT, 0, stream>>>(yin, uout, bsums, yout);
}